// Round 11
// baseline (212.783 us; speedup 1.0000x reference)
//
#include <hip/hip_runtime.h>
#include <hip/hip_bf16.h>

// DRL4Metro pointer-network decode, MI355X persistent kernel.
// B=8, S=8192, H=128, steps=20 (read from d_in[19]).
// Grid 256x256; 8 groups (one per batch) of 32 blocks.
//
// R11 = R10 transport minus tail syncs, all hot-loop lines pre-warmed:
//  - krec published PER WAVE (slot blk*4+wv) into warm double-buffered slots
//    right after the wave key-max: no post-attention __syncthreads at all.
//    Consumers read 2 krecs/lane (128 records) -> full group max in-wave.
//  - frec per-WAVE, per-STEP slots, consumed ONLY in the epilogue (R9-style,
//    absmax-0-verified). No in-loop frec poll (blk0 drag gone).
//  - ALL record buffers warmed at startup (tag-0 dummy stores by the same
//    threads that later publish; drained by the startup __syncthreads).
//    Mechanism: vmcnt is a single counter -- a pending cold-line store
//    (~1us write-allocate) blocks the publisher wave's next spin waitcnt
//    (R7/R8/R9 regressions). Warm lines retire at L2 speed.
// Records (agent scope sc0 sc1, IC-coherent, self-tagged):
//   krec u64 {tag=t+1 | wkey}; wkey=(k+8192)<<13|(8191-ix), k = exact 2^-10
//        bucket of attn+10000.0f -> u32 max == (max, first-index).
//   hh   u64 {tag=t+1 | h@W_hh row bits}, 16/block, double-buffered warm.
//   frec u64 {esum_w | tag(5)<<27 | wkey}, per-wave per-step, warm.
// Tags: poison 0xAA... = 21 / dummy 0, never matching expected 1..20.
// Slot reuse separated from last read by a full barrier generation.

#define SS 8192
#define HH 128
#define NB 8

constexpr float kLog2e  = 1.4426950408889634f;
constexpr float kLn2    = 0.6931471805599453f;
constexpr float kBucket = 9.765625e-4f;            // 2^-10
constexpr float kBL2e   = kLog2e * 9.765625e-4f;   // 2^-10 * log2e

__device__ __forceinline__ float fsig(float x) {
  return __builtin_amdgcn_rcpf(1.0f + __builtin_amdgcn_exp2f(-x * kLog2e));
}
__device__ __forceinline__ float ftanh(float x) {
  float z = __builtin_amdgcn_exp2f(x * (2.0f * kLog2e));
  return fmaf(-2.0f, __builtin_amdgcn_rcpf(z + 1.0f), 1.0f);
}

__device__ __forceinline__ unsigned long long cld64(const unsigned long long* p) {
  return __hip_atomic_load(p, __ATOMIC_RELAXED, __HIP_MEMORY_SCOPE_AGENT);
}
__device__ __forceinline__ void cst64(unsigned long long* p, unsigned long long v) {
  __hip_atomic_store(p, v, __ATOMIC_RELAXED, __HIP_MEMORY_SCOPE_AGENT);
}

__global__ __launch_bounds__(256, 1)
void drl4_kernel(const float* __restrict__ g_static,
                 const float* __restrict__ g_dynamic,
                 const float* __restrict__ W_s,  const float* __restrict__ b_s,
                 const float* __restrict__ W_d,  const float* __restrict__ b_d,
                 const float* __restrict__ W_dec,const float* __restrict__ b_dec,
                 const float* __restrict__ W_ih, const float* __restrict__ W_hh,
                 const float* __restrict__ b_ih, const float* __restrict__ b_hh,
                 const float* __restrict__ W_ref,const float* __restrict__ b_ref,
                 const float* __restrict__ W_pd, const float* __restrict__ b_pd,
                 const float* __restrict__ W_q,  const float* __restrict__ b_q,
                 const float* __restrict__ W_att,const int* __restrict__ steps_p,
                 float* __restrict__ out,
                 unsigned long long* __restrict__ krec,
                 unsigned long long* __restrict__ frec,
                 unsigned long long* __restrict__ hhrec) {
  const int tid = threadIdx.x;
  const int bid = blockIdx.x;
  const int b   = bid >> 5;   // batch / group id
  const int blk = bid & 31;   // block within group
  const int steps = *steps_p;

  __shared__ float4 s_pack[128];   // startup only: {A0,A1,C}*2log2e, W_att
  __shared__ float  s_ebias[128];  // W_ref@b_s + b_ref + W_pd@b_d + b_pd + b_q
  __shared__ float  s_gb[512];     // W_ih@b_dec + b_ih + b_hh
  __shared__ float  s_g1x[512];    // W_ih @ W_dec col0
  __shared__ float  s_g1y[512];    // W_ih @ W_dec col1
  __shared__ float  s_h[128];      // current LSTM hidden (this batch)
  __shared__ __align__(16) float s_qe[128];  // exp2((q+ebias)*2log2e)
  __shared__ float  s_scr[256];

  // each thread owns exactly one city of this batch
  const int city = blk * 256 + tid;
  const float sx = g_static[(b * 2 + 0) * SS + city];
  const float sy = g_static[(b * 2 + 1) * SS + city];
  const float dd = g_dynamic[b * SS + city];

  const int wv = tid >> 6;      // wave id
  const int ln = tid & 63;      // lane id

  // ---- persistent register fragments (loaded once) -----------------------
  const int qrow  = (tid >> 6) * 32 + (tid & 31);
  const int qhalf = (tid >> 5) & 1;
  float wq[64];
  {
    const float* p = W_q + qrow * HH + qhalf * 64;
    #pragma unroll
    for (int j = 0; j < 64; j += 4) {
      float4 v = *(const float4*)(p + j);
      wq[j] = v.x; wq[j+1] = v.y; wq[j+2] = v.z; wq[j+3] = v.w;
    }
  }
  // W_hh fragment: block owns gate rows [blk*16, blk*16+16).
  const int ho = tid & 15, hk = tid >> 4;
  float whh[8];
  {
    const float* p = W_hh + (blk * 16 + ho) * HH + hk * 8;
    #pragma unroll
    for (int j = 0; j < 8; j += 4) {
      float4 v = *(const float4*)(p + j);
      whh[j] = v.x; whh[j+1] = v.y; whh[j+2] = v.z; whh[j+3] = v.w;
    }
  }

  // ---- warm all record lines this thread will later publish --------------
  // (tag-0 dummies; drained by the __syncthreads below, so the later real
  //  stores from the same threads can never be reordered ahead of them)
  if (ln == 0) {
    cst64(krec + 0 * 1024 + b * 128 + blk * 4 + wv, 0ull);
    cst64(krec + 1 * 1024 + b * 128 + blk * 4 + wv, 0ull);
    for (int s = 0; s < steps; ++s)
      cst64(frec + (s * 8 + b) * 128 + blk * 4 + wv, 0ull);
  }
  if (tid < 16) {
    cst64(hhrec + 0 * 4096 + b * 512 + blk * 16 + tid, 0ull);
    cst64(hhrec + 1 * 4096 + b * 512 + blk * 16 + tid, 0ull);
  }

  // ---- one-time per-block precompute (collapsed linear algebra) ----------
  for (int g = tid; g < 512; g += 256) {
    const float* wr = W_ih + g * HH;
    float acc = b_ih[g] + b_hh[g];
    float ax = 0.f, ay = 0.f;
    for (int k = 0; k < HH; k += 4) {
      float4 w  = *(const float4*)(wr + k);
      float4 bd = *(const float4*)(b_dec + k);
      float4 d0 = *(const float4*)(W_dec + 2 * k);
      float4 d1 = *(const float4*)(W_dec + 2 * k + 4);
      acc = fmaf(w.x, bd.x, acc); ax = fmaf(w.x, d0.x, ax); ay = fmaf(w.x, d0.y, ay);
      acc = fmaf(w.y, bd.y, acc); ax = fmaf(w.y, d0.z, ax); ay = fmaf(w.y, d0.w, ay);
      acc = fmaf(w.z, bd.z, acc); ax = fmaf(w.z, d1.x, ax); ay = fmaf(w.z, d1.y, ay);
      acc = fmaf(w.w, bd.w, acc); ax = fmaf(w.w, d1.z, ax); ay = fmaf(w.w, d1.w, ay);
    }
    s_gb[g] = acc; s_g1x[g] = ax; s_g1y[g] = ay;
  }
  if (tid < 128) {
    float a0 = 0.f, a1 = 0.f, c0 = 0.f, e1 = 0.f, e2 = 0.f;
    const float* wr = W_ref + tid * HH;
    const float* wp = W_pd  + tid * HH;
    for (int k = 0; k < HH; k += 4) {
      float4 w  = *(const float4*)(wr + k);
      float4 v  = *(const float4*)(wp + k);
      float4 s0 = *(const float4*)(W_s + 2 * k);
      float4 s1 = *(const float4*)(W_s + 2 * k + 4);
      float4 bs = *(const float4*)(b_s + k);
      float4 wd = *(const float4*)(W_d + k);
      float4 bd = *(const float4*)(b_d + k);
      a0 = fmaf(w.x, s0.x, a0); a1 = fmaf(w.x, s0.y, a1); e1 = fmaf(w.x, bs.x, e1);
      c0 = fmaf(v.x, wd.x, c0); e2 = fmaf(v.x, bd.x, e2);
      a0 = fmaf(w.y, s0.z, a0); a1 = fmaf(w.y, s0.w, a1); e1 = fmaf(w.y, bs.y, e1);
      c0 = fmaf(v.y, wd.y, c0); e2 = fmaf(v.y, bd.y, e2);
      a0 = fmaf(w.z, s1.x, a0); a1 = fmaf(w.z, s1.y, a1); e1 = fmaf(w.z, bs.z, e1);
      c0 = fmaf(v.z, wd.z, c0); e2 = fmaf(v.z, bd.z, e2);
      a0 = fmaf(w.w, s1.z, a0); a1 = fmaf(w.w, s1.w, a1); e1 = fmaf(w.w, bs.w, e1);
      c0 = fmaf(v.w, wd.w, c0); e2 = fmaf(v.w, bd.w, e2);
    }
    const float sc = 2.0f * kLog2e;   // pre-fold tanh's 2*log2e scaling
    s_pack[tid]  = make_float4(a0 * sc, a1 * sc, c0 * sc, W_att[tid]);
    s_ebias[tid] = e1 + e2 + b_ref[tid] + b_pd[tid] + b_q[tid];
  }
  float cstate = 0.0f;   // LSTM cell state for (b, tid) — threads tid<128
  __syncthreads();       // drains warm stores + publishes LDS precompute

  // ---- per-thread step-invariant attention state -------------------------
  float zb[128], watt[128];
  #pragma unroll
  for (int h = 0; h < 128; ++h) {
    float4 p = s_pack[h];
    zb[h]   = __builtin_amdgcn_exp2f(fmaf(p.x, sx, fmaf(p.y, sy, p.z * dd)));
    watt[h] = p.w;
  }

  for (int t = 0; t < steps; ++t) {
    // ---- stage 1: pipelined spin = barrier + argmax + LSTM inputs --------
    float hp0 = 0.f, hp1 = 0.f, hp2 = 0.f, hp3 = 0.f;
    float selx = 0.f, sely = 0.f;
    if (t > 0) {
      if (tid < 128) {   // waves 0,1: the hot path
        const unsigned expect = (unsigned)t;
        const unsigned long long* kp =
            krec + ((t - 1) & 1) * 1024 + b * 128 + ln;
        const unsigned long long* hp = hhrec + (t & 1) * 4096 + b * 512 + tid;
        unsigned long long kv0, kv1, h0, h1, h2, h3;
        {
          unsigned long long aj, ak, a0, a1, a2, a3;
          unsigned long long bj, bk, b0, b1, b2, b3;
          aj = cld64(kp);       ak = cld64(kp + 64);
          a0 = cld64(hp);       a1 = cld64(hp + 128);
          a2 = cld64(hp + 256); a3 = cld64(hp + 384);
          for (;;) {
            asm volatile("" ::: "memory");
            bj = cld64(kp);       bk = cld64(kp + 64);
            b0 = cld64(hp);       b1 = cld64(hp + 128);
            b2 = cld64(hp + 256); b3 = cld64(hp + 384);
            asm volatile("" ::: "memory");
            if ((unsigned)(aj >> 32) == expect && (unsigned)(ak >> 32) == expect &&
                (unsigned)(a0 >> 32) == expect && (unsigned)(a1 >> 32) == expect &&
                (unsigned)(a2 >> 32) == expect && (unsigned)(a3 >> 32) == expect) {
              kv0 = aj; kv1 = ak; h0 = a0; h1 = a1; h2 = a2; h3 = a3; break;
            }
            asm volatile("" ::: "memory");
            aj = cld64(kp);       ak = cld64(kp + 64);
            a0 = cld64(hp);       a1 = cld64(hp + 128);
            a2 = cld64(hp + 256); a3 = cld64(hp + 384);
            asm volatile("" ::: "memory");
            if ((unsigned)(bj >> 32) == expect && (unsigned)(bk >> 32) == expect &&
                (unsigned)(b0 >> 32) == expect && (unsigned)(b1 >> 32) == expect &&
                (unsigned)(b2 >> 32) == expect && (unsigned)(b3 >> 32) == expect) {
              kv0 = bj; kv1 = bk; h0 = b0; h1 = b1; h2 = b2; h3 = b3; break;
            }
          }
        }
        // speculative winner-coords gather on my local candidate; winner
        // delivered via shfl broadcast after the in-wave 128-record max.
        unsigned u0 = (unsigned)kv0, u1 = (unsigned)kv1;
        const unsigned myk = u0 > u1 ? u0 : u1;
        const int my_ix = 8191 - (int)(myk & 0x1FFFu);
        const float* gsb = g_static + (b * 2) * SS;
        float cx = gsb[my_ix];
        float cy = gsb[SS + my_ix];
        unsigned wmax = myk;
        #pragma unroll
        for (int k = 1; k < 64; k <<= 1) {
          unsigned o = __shfl_xor(wmax, k);
          wmax = wmax > o ? wmax : o;
        }
        unsigned long long win = __ballot(myk == wmax);
        int src = __ffsll(win) - 1;
        selx = __shfl(cx, src);
        sely = __shfl(cy, src);
        hp0 = __uint_as_float((unsigned)h0);
        hp1 = __uint_as_float((unsigned)h1);
        hp2 = __uint_as_float((unsigned)h2);
        hp3 = __uint_as_float((unsigned)h3);
      }
    }
    // ---- stage 2: LSTM cell (threads tid<128) ----------------------------
    if (tid < 128) {
      float gi, gf, gg, go;
      if (t == 0) {   // dec_in = 0, h = 0 → gates are just the bias term
        gi = s_gb[tid];       gf = s_gb[tid + 128];
        gg = s_gb[tid + 256]; go = s_gb[tid + 384];
      } else {
        gi = fmaf(selx, s_g1x[tid],     fmaf(sely, s_g1y[tid],     s_gb[tid]     + hp0));
        gf = fmaf(selx, s_g1x[tid+128], fmaf(sely, s_g1y[tid+128], s_gb[tid+128] + hp1));
        gg = fmaf(selx, s_g1x[tid+256], fmaf(sely, s_g1y[tid+256], s_gb[tid+256] + hp2));
        go = fmaf(selx, s_g1x[tid+384], fmaf(sely, s_g1y[tid+384], s_gb[tid+384] + hp3));
      }
      cstate  = fmaf(fsig(gf), cstate, fsig(gi) * ftanh(gg));
      s_h[tid] = fsig(go) * ftanh(cstate);
    }
    __syncthreads();
    // ---- stage 2b: q = h @ W_q.T (shfl-combined halves) ------------------
    {
      const float* hs = s_h + (qhalf << 6);
      float qa = 0.f;
      #pragma unroll
      for (int u = 0; u < 64; ++u) qa = fmaf(wq[u], hs[u], qa);
      float qo = __shfl_xor(qa, 32);
      if (qhalf == 0) {
        float qe = (qa + qo + s_ebias[qrow]) * (2.0f * kLog2e);
        s_qe[qrow] = __builtin_amdgcn_exp2f(qe);
      }
    }
    // ---- stage 3: next step's h @ W_hh.T partial -------------------------
    {
      const float* hs2 = s_h + hk * 8;
      float pa = 0.f;
      #pragma unroll
      for (int u = 0; u < 8; ++u) pa = fmaf(whh[u], hs2[u], pa);
      s_scr[tid] = pa;
    }
    __syncthreads();
    if (tid < 16) {   // publish self-tagged hh rows; land during attention
      float acc = 0.f;
      #pragma unroll
      for (int j = 0; j < 16; ++j) acc += s_scr[j * 16 + tid];
      cst64(hhrec + ((t + 1) & 1) * 4096 + b * 512 + blk * 16 + tid,
            ((unsigned long long)(unsigned)(t + 1) << 32) |
                __float_as_uint(acc));
    }
    // ---- stage 4: attention (bit-identical arithmetic) -------------------
    float a0 = 0.f, a1 = 0.f, a2 = 0.f, a3 = 0.f;
    #pragma unroll
    for (int h = 0; h < 128; h += 4) {
      float4 zq = *(const float4*)(s_qe + h);
      float z0 = zb[h+0] * zq.x, z1 = zb[h+1] * zq.y;
      float z2 = zb[h+2] * zq.z, z3 = zb[h+3] * zq.w;
      float r0 = __builtin_amdgcn_rcpf(z0 + 1.0f);
      float r1 = __builtin_amdgcn_rcpf(z1 + 1.0f);
      float r2 = __builtin_amdgcn_rcpf(z2 + 1.0f);
      float r3 = __builtin_amdgcn_rcpf(z3 + 1.0f);
      a0 = fmaf(watt[h+0], fmaf(-2.0f, r0, 1.0f), a0);
      a1 = fmaf(watt[h+1], fmaf(-2.0f, r1, 1.0f), a1);
      a2 = fmaf(watt[h+2], fmaf(-2.0f, r2, 1.0f), a2);
      a3 = fmaf(watt[h+3], fmaf(-2.0f, r3, 1.0f), a3);
    }
    float aq = ((a0 + a1) + (a2 + a3)) + 10000.0f;   // 2^-10-bucket quantized
    int kk = (int)((aq - 10000.0f) * 1024.0f);       // exact bucket index
    kk = kk < -8192 ? -8192 : (kk > 8191 ? 8191 : kk);
    unsigned key = ((unsigned)(kk + 8192) << 13) | (unsigned)(8191 - city);
    unsigned wmax = key;
    #pragma unroll
    for (int k = 1; k < 64; k <<= 1) {
      unsigned o = __shfl_xor(wmax, k);
      wmax = wmax > o ? wmax : o;
    }
    if (ln == 0)   // EARLY per-wave publish to WARM slot (no block combine)
      cst64(krec + (t & 1) * 1024 + b * 128 + blk * 4 + wv,
            ((unsigned long long)(unsigned)(t + 1) << 32) | wmax);
    // ---- sumexp path (per-wave frec, warm per-step slots; epilogue-only) -
    float m_w = fmaf((float)((int)((wmax >> 13) & 0x3FFFu) - 8192), kBucket,
                     10000.0f);
    float ee = __builtin_amdgcn_exp2f((aq - m_w) * kLog2e);   // exact diff
    #pragma unroll
    for (int k = 1; k < 64; k <<= 1) ee += __shfl_xor(ee, k);
    if (ln == 0)
      cst64(frec + (t * 8 + b) * 128 + blk * 4 + wv,
            ((unsigned long long)__float_as_uint(ee) << 32) |
                ((unsigned)(t + 1) << 27) | wmax);
    // no end-of-step barrier: next iteration's spin is the barrier
  }
  // ---- epilogue: leader blocks write all outputs from frec history -------
  if (blk == 0) {
    for (int s = wv; s < steps; s += 4) {
      const unsigned long long* wp = frec + (s * 8 + b) * 128;
      const unsigned expect = (unsigned)(s + 1);
      unsigned long long r0, r1;
      for (;;) {
        r0 = cld64(wp + ln); r1 = cld64(wp + 64 + ln);
        if (((unsigned)r0 >> 27) == expect && ((unsigned)r1 >> 27) == expect)
          break;
        __builtin_amdgcn_s_sleep(1);
      }
      unsigned k0 = (unsigned)r0 & 0x07FFFFFFu;
      unsigned k1 = (unsigned)r1 & 0x07FFFFFFu;
      unsigned wmax = k0 > k1 ? k0 : k1;
      #pragma unroll
      for (int k = 1; k < 64; k <<= 1) {
        unsigned o = __shfl_xor(wmax, k);
        wmax = wmax > o ? wmax : o;
      }
      int K  = (int)((wmax >> 13) & 0x3FFFu) - 8192;
      int i0 = (int)((k0 >> 13) & 0x3FFFu) - 8192;
      int i1 = (int)((k1 >> 13) & 0x3FFFu) - 8192;
      float e0 = __uint_as_float((unsigned)(r0 >> 32));
      float e1 = __uint_as_float((unsigned)(r1 >> 32));
      float term = fmaf(e0, __builtin_amdgcn_exp2f((float)(i0 - K) * kBL2e),
                        e1 * __builtin_amdgcn_exp2f((float)(i1 - K) * kBL2e));
      #pragma unroll
      for (int k = 1; k < 64; k <<= 1) term += __shfl_xor(term, k);
      if (ln == 0) {
        out[b * steps + s] = (float)(8191 - (int)(wmax & 0x1FFFu));
        out[NB * steps + b * steps + s] =
            -__builtin_amdgcn_logf(term) * kLn2;
      }
    }
  }
}

extern "C" void kernel_launch(void* const* d_in, const int* in_sizes, int n_in,
                              void* d_out, int out_size, void* d_ws, size_t ws_size,
                              hipStream_t stream) {
  // ws layout (self-initializing + startup-warmed; no memset):
  //   [0, 16K)     krec : u64[2][8][128]  per-wave, warm dbuf
  //   [16K, 176K)  frec : u64[20][8][128] per-wave per-step, warmed, epilogue
  //   [176K, 240K) hhrec: u64[2][8*512]   warm dbuf
  unsigned long long* krec  = (unsigned long long*)d_ws;
  unsigned long long* frec  = (unsigned long long*)((char*)d_ws + 16384);
  unsigned long long* hhrec = (unsigned long long*)((char*)d_ws + 180224);
  drl4_kernel<<<dim3(256), dim3(256), 0, stream>>>(
      (const float*)d_in[0],  (const float*)d_in[1],
      (const float*)d_in[2],  (const float*)d_in[3],
      (const float*)d_in[4],  (const float*)d_in[5],
      (const float*)d_in[6],  (const float*)d_in[7],
      (const float*)d_in[8],  (const float*)d_in[9],
      (const float*)d_in[10], (const float*)d_in[11],
      (const float*)d_in[12], (const float*)d_in[13],
      (const float*)d_in[14], (const float*)d_in[15],
      (const float*)d_in[16], (const float*)d_in[17],
      (const float*)d_in[18], (const int*)d_in[19],
      (float*)d_out, krec, frec, hhrec);
}

// Round 12
// 195.867 us; speedup vs baseline: 1.0864x; 1.0864x over previous
//
#include <hip/hip_runtime.h>
#include <hip/hip_bf16.h>

// DRL4Metro pointer-network decode, MI355X persistent kernel.
// B=8, S=8192, H=128, steps=20 (read from d_in[19]).
// Grid 256x256; 8 groups (one per batch) of 32 blocks.
//
// R12 = R10 verbatim (proven best: 111.2us profiled). The R6/R10 structure
// is a sharp local optimum: R7/R8/R9/R11 each deviated on one component
// (per-step slots, L2 fast path, per-wave publish, cold-line warming) and
// all regressed 12-31us. Floor terms per step: ~1.3us agent-scope IC
// publish->detect RT (hardware), ~1us group straggler (max over 32 blocks),
// ~1.7us VALU, ~0.5us intra-block syncs.
// Records (agent scope sc0 sc1, IC-coherent, self-tagged, ALL warm dbuf —
// vmcnt is a single counter; any cold-line store in the hot loop stalls the
// publisher wave's next spin waitcnt by ~1us write-allocate):
//   krec u64 {tag=t+1 | bkey}, 1/block. bkey=(k+8192)<<13|(8191-ix), k =
//        exact 2^-10 bucket of attn+10000.0f (the reference's f32
//        softmax(attns+10000) quantization) -> u32 max == (max, first-idx).
//   hh   u64 {tag=t+1 | h@W_hh row bits}, 16/block.
//   frec u64 {S | tag(5)<<27|bkey}, 1/block; polled in-loop only by wave 2
//        of each group leader (output writer).
// 0xAA poison gives tags 21/0xAAAAAAAA, never matching expected 1..20;
// slot reuse is separated from last read by a full barrier generation.

#define SS 8192
#define HH 128
#define NB 8

constexpr float kLog2e  = 1.4426950408889634f;
constexpr float kLn2    = 0.6931471805599453f;
constexpr float kBucket = 9.765625e-4f;            // 2^-10
constexpr float kBL2e   = kLog2e * 9.765625e-4f;   // 2^-10 * log2e

__device__ __forceinline__ float fsig(float x) {
  return __builtin_amdgcn_rcpf(1.0f + __builtin_amdgcn_exp2f(-x * kLog2e));
}
__device__ __forceinline__ float ftanh(float x) {
  float z = __builtin_amdgcn_exp2f(x * (2.0f * kLog2e));
  return fmaf(-2.0f, __builtin_amdgcn_rcpf(z + 1.0f), 1.0f);
}

__device__ __forceinline__ unsigned long long cld64(const unsigned long long* p) {
  return __hip_atomic_load(p, __ATOMIC_RELAXED, __HIP_MEMORY_SCOPE_AGENT);
}
__device__ __forceinline__ void cst64(unsigned long long* p, unsigned long long v) {
  __hip_atomic_store(p, v, __ATOMIC_RELAXED, __HIP_MEMORY_SCOPE_AGENT);
}

__global__ __launch_bounds__(256, 1)
void drl4_kernel(const float* __restrict__ g_static,
                 const float* __restrict__ g_dynamic,
                 const float* __restrict__ W_s,  const float* __restrict__ b_s,
                 const float* __restrict__ W_d,  const float* __restrict__ b_d,
                 const float* __restrict__ W_dec,const float* __restrict__ b_dec,
                 const float* __restrict__ W_ih, const float* __restrict__ W_hh,
                 const float* __restrict__ b_ih, const float* __restrict__ b_hh,
                 const float* __restrict__ W_ref,const float* __restrict__ b_ref,
                 const float* __restrict__ W_pd, const float* __restrict__ b_pd,
                 const float* __restrict__ W_q,  const float* __restrict__ b_q,
                 const float* __restrict__ W_att,const int* __restrict__ steps_p,
                 float* __restrict__ out,
                 unsigned long long* __restrict__ krec,
                 unsigned long long* __restrict__ frec,
                 unsigned long long* __restrict__ hhrec) {
  const int tid = threadIdx.x;
  const int bid = blockIdx.x;
  const int b   = bid >> 5;   // batch / group id
  const int blk = bid & 31;   // block within group
  const int steps = *steps_p;

  __shared__ float4 s_pack[128];   // startup only: {A0,A1,C}*2log2e, W_att
  __shared__ float  s_ebias[128];  // W_ref@b_s + b_ref + W_pd@b_d + b_pd + b_q
  __shared__ float  s_gb[512];     // W_ih@b_dec + b_ih + b_hh
  __shared__ float  s_g1x[512];    // W_ih @ W_dec col0
  __shared__ float  s_g1y[512];    // W_ih @ W_dec col1
  __shared__ float  s_h[128];      // current LSTM hidden (this batch)
  __shared__ __align__(16) float s_qe[128];  // exp2((q+ebias)*2log2e)
  __shared__ float  s_scr[256];
  __shared__ unsigned s_wk[4];
  __shared__ float  s_we[4];

  // each thread owns exactly one city of this batch
  const int city = blk * 256 + tid;
  const float sx = g_static[(b * 2 + 0) * SS + city];
  const float sy = g_static[(b * 2 + 1) * SS + city];
  const float dd = g_dynamic[b * SS + city];

  // ---- persistent register fragments (loaded once) -----------------------
  const int qrow  = (tid >> 6) * 32 + (tid & 31);
  const int qhalf = (tid >> 5) & 1;
  float wq[64];
  {
    const float* p = W_q + qrow * HH + qhalf * 64;
    #pragma unroll
    for (int j = 0; j < 64; j += 4) {
      float4 v = *(const float4*)(p + j);
      wq[j] = v.x; wq[j+1] = v.y; wq[j+2] = v.z; wq[j+3] = v.w;
    }
  }
  // W_hh fragment: block owns gate rows [blk*16, blk*16+16).
  const int ho = tid & 15, hk = tid >> 4;
  float whh[8];
  {
    const float* p = W_hh + (blk * 16 + ho) * HH + hk * 8;
    #pragma unroll
    for (int j = 0; j < 8; j += 4) {
      float4 v = *(const float4*)(p + j);
      whh[j] = v.x; whh[j+1] = v.y; whh[j+2] = v.z; whh[j+3] = v.w;
    }
  }

  // ---- one-time per-block precompute (collapsed linear algebra) ----------
  for (int g = tid; g < 512; g += 256) {
    const float* wr = W_ih + g * HH;
    float acc = b_ih[g] + b_hh[g];
    float ax = 0.f, ay = 0.f;
    for (int k = 0; k < HH; k += 4) {
      float4 w  = *(const float4*)(wr + k);
      float4 bd = *(const float4*)(b_dec + k);
      float4 d0 = *(const float4*)(W_dec + 2 * k);
      float4 d1 = *(const float4*)(W_dec + 2 * k + 4);
      acc = fmaf(w.x, bd.x, acc); ax = fmaf(w.x, d0.x, ax); ay = fmaf(w.x, d0.y, ay);
      acc = fmaf(w.y, bd.y, acc); ax = fmaf(w.y, d0.z, ax); ay = fmaf(w.y, d0.w, ay);
      acc = fmaf(w.z, bd.z, acc); ax = fmaf(w.z, d1.x, ax); ay = fmaf(w.z, d1.y, ay);
      acc = fmaf(w.w, bd.w, acc); ax = fmaf(w.w, d1.z, ax); ay = fmaf(w.w, d1.w, ay);
    }
    s_gb[g] = acc; s_g1x[g] = ax; s_g1y[g] = ay;
  }
  if (tid < 128) {
    float a0 = 0.f, a1 = 0.f, c0 = 0.f, e1 = 0.f, e2 = 0.f;
    const float* wr = W_ref + tid * HH;
    const float* wp = W_pd  + tid * HH;
    for (int k = 0; k < HH; k += 4) {
      float4 w  = *(const float4*)(wr + k);
      float4 v  = *(const float4*)(wp + k);
      float4 s0 = *(const float4*)(W_s + 2 * k);
      float4 s1 = *(const float4*)(W_s + 2 * k + 4);
      float4 bs = *(const float4*)(b_s + k);
      float4 wd = *(const float4*)(W_d + k);
      float4 bd = *(const float4*)(b_d + k);
      a0 = fmaf(w.x, s0.x, a0); a1 = fmaf(w.x, s0.y, a1); e1 = fmaf(w.x, bs.x, e1);
      c0 = fmaf(v.x, wd.x, c0); e2 = fmaf(v.x, bd.x, e2);
      a0 = fmaf(w.y, s0.z, a0); a1 = fmaf(w.y, s0.w, a1); e1 = fmaf(w.y, bs.y, e1);
      c0 = fmaf(v.y, wd.y, c0); e2 = fmaf(v.y, bd.y, e2);
      a0 = fmaf(w.z, s1.x, a0); a1 = fmaf(w.z, s1.y, a1); e1 = fmaf(w.z, bs.z, e1);
      c0 = fmaf(v.z, wd.z, c0); e2 = fmaf(v.z, bd.z, e2);
      a0 = fmaf(w.w, s1.z, a0); a1 = fmaf(w.w, s1.w, a1); e1 = fmaf(w.w, bs.w, e1);
      c0 = fmaf(v.w, wd.w, c0); e2 = fmaf(v.w, bd.w, e2);
    }
    const float sc = 2.0f * kLog2e;   // pre-fold tanh's 2*log2e scaling
    s_pack[tid]  = make_float4(a0 * sc, a1 * sc, c0 * sc, W_att[tid]);
    s_ebias[tid] = e1 + e2 + b_ref[tid] + b_pd[tid] + b_q[tid];
  }
  float cstate = 0.0f;   // LSTM cell state for (b, tid) — threads tid<128
  __syncthreads();

  // ---- per-thread step-invariant attention state -------------------------
  float zb[128], watt[128];
  #pragma unroll
  for (int h = 0; h < 128; ++h) {
    float4 p = s_pack[h];
    zb[h]   = __builtin_amdgcn_exp2f(fmaf(p.x, sx, fmaf(p.y, sy, p.z * dd)));
    watt[h] = p.w;
  }

  const int wv = tid >> 6;      // wave id
  const int ln = tid & 63;      // lane id
  for (int t = 0; t < steps; ++t) {
    // ---- stage 1: pipelined spin = barrier + argmax + LSTM inputs --------
    float hp0 = 0.f, hp1 = 0.f, hp2 = 0.f, hp3 = 0.f;
    float selx = 0.f, sely = 0.f;
    if (t > 0) {
      if (tid < 128) {   // waves 0,1: the hot path
        const unsigned expect = (unsigned)t;
        const unsigned long long* kp =
            krec + ((t - 1) & 1) * 512 + b * 64 + (tid & 31);
        const unsigned long long* hp = hhrec + (t & 1) * 4096 + b * 512 + tid;
        unsigned long long kv, h0, h1, h2, h3;
        {
          unsigned long long ak, a0, a1, a2, a3;
          unsigned long long bk, b0, b1, b2, b3;
          ak = cld64(kp);
          a0 = cld64(hp);       a1 = cld64(hp + 128);
          a2 = cld64(hp + 256); a3 = cld64(hp + 384);
          for (;;) {
            asm volatile("" ::: "memory");
            bk = cld64(kp);
            b0 = cld64(hp);       b1 = cld64(hp + 128);
            b2 = cld64(hp + 256); b3 = cld64(hp + 384);
            asm volatile("" ::: "memory");
            if ((unsigned)(ak >> 32) == expect && (unsigned)(a0 >> 32) == expect &&
                (unsigned)(a1 >> 32) == expect && (unsigned)(a2 >> 32) == expect &&
                (unsigned)(a3 >> 32) == expect) {
              kv = ak; h0 = a0; h1 = a1; h2 = a2; h3 = a3; break;
            }
            asm volatile("" ::: "memory");
            ak = cld64(kp);
            a0 = cld64(hp);       a1 = cld64(hp + 128);
            a2 = cld64(hp + 256); a3 = cld64(hp + 384);
            asm volatile("" ::: "memory");
            if ((unsigned)(bk >> 32) == expect && (unsigned)(b0 >> 32) == expect &&
                (unsigned)(b1 >> 32) == expect && (unsigned)(b2 >> 32) == expect &&
                (unsigned)(b3 >> 32) == expect) {
              kv = bk; h0 = b0; h1 = b1; h2 = b2; h3 = b3; break;
            }
          }
        }
        // speculative winner-coords gather: issue my candidate's loads now,
        // overlap with the max-reduce; winner broadcast via shfl.
        const unsigned myk = (unsigned)kv;
        const int my_ix = 8191 - (int)(myk & 0x1FFFu);
        const float* gsb = g_static + (b * 2) * SS;
        float cx = gsb[my_ix];
        float cy = gsb[SS + my_ix];
        unsigned wmax = myk;
        #pragma unroll
        for (int k = 1; k < 64; k <<= 1) {
          unsigned o = __shfl_xor(wmax, k);
          wmax = wmax > o ? wmax : o;
        }
        unsigned long long win = __ballot(myk == wmax);
        int src = __ffsll(win) - 1;
        selx = __shfl(cx, src);
        sely = __shfl(cy, src);
        hp0 = __uint_as_float((unsigned)h0);
        hp1 = __uint_as_float((unsigned)h1);
        hp2 = __uint_as_float((unsigned)h2);
        hp3 = __uint_as_float((unsigned)h3);
      } else if (blk == 0 && tid < 192) {
        // wave 2 of group leader: frec poll + outputs for step t-1
        const unsigned expect = (unsigned)t;   // 5-bit tag
        const unsigned long long* fp =
            frec + ((t - 1) & 1) * 512 + b * 64 + (tid & 31);
        unsigned long long rv;
        for (;;) {
          rv = cld64(fp);
          if (((unsigned)rv >> 27) == expect) break;
          __builtin_amdgcn_s_sleep(1);
        }
        unsigned wmax = (unsigned)rv & 0x07FFFFFFu;
        #pragma unroll
        for (int k = 1; k < 64; k <<= 1) {
          unsigned o = __shfl_xor(wmax, k);
          wmax = wmax > o ? wmax : o;
        }
        int   ixf = 8191 - (int)(wmax & 0x1FFFu);
        int   kb  = (int)(((unsigned)rv >> 13) & 0x3FFFu) - 8192;
        int   K   = (int)((wmax >> 13) & 0x3FFFu) - 8192;
        float Sb  = __uint_as_float((unsigned)(rv >> 32));
        float term = Sb * __builtin_amdgcn_exp2f((float)(kb - K) * kBL2e);
        #pragma unroll
        for (int k = 1; k < 32; k <<= 1) term += __shfl_xor(term, k, 32);
        if (tid == 128) {
          out[b * steps + (t - 1)] = (float)ixf;
          out[NB * steps + b * steps + (t - 1)] =
              -__builtin_amdgcn_logf(term) * kLn2;
        }
      }
    }
    // ---- stage 2: LSTM cell (threads tid<128) ----------------------------
    if (tid < 128) {
      float gi, gf, gg, go;
      if (t == 0) {   // dec_in = 0, h = 0 → gates are just the bias term
        gi = s_gb[tid];       gf = s_gb[tid + 128];
        gg = s_gb[tid + 256]; go = s_gb[tid + 384];
      } else {
        gi = fmaf(selx, s_g1x[tid],     fmaf(sely, s_g1y[tid],     s_gb[tid]     + hp0));
        gf = fmaf(selx, s_g1x[tid+128], fmaf(sely, s_g1y[tid+128], s_gb[tid+128] + hp1));
        gg = fmaf(selx, s_g1x[tid+256], fmaf(sely, s_g1y[tid+256], s_gb[tid+256] + hp2));
        go = fmaf(selx, s_g1x[tid+384], fmaf(sely, s_g1y[tid+384], s_gb[tid+384] + hp3));
      }
      cstate  = fmaf(fsig(gf), cstate, fsig(gi) * ftanh(gg));
      s_h[tid] = fsig(go) * ftanh(cstate);
    }
    __syncthreads();
    // ---- stage 2b: q = h @ W_q.T (shfl-combined halves) ------------------
    {
      const float* hs = s_h + (qhalf << 6);
      float qa = 0.f;
      #pragma unroll
      for (int u = 0; u < 64; ++u) qa = fmaf(wq[u], hs[u], qa);
      float qo = __shfl_xor(qa, 32);
      if (qhalf == 0) {
        float qe = (qa + qo + s_ebias[qrow]) * (2.0f * kLog2e);
        s_qe[qrow] = __builtin_amdgcn_exp2f(qe);
      }
    }
    // ---- stage 3: next step's h @ W_hh.T partial -------------------------
    {
      const float* hs2 = s_h + hk * 8;
      float pa = 0.f;
      #pragma unroll
      for (int u = 0; u < 8; ++u) pa = fmaf(whh[u], hs2[u], pa);
      s_scr[tid] = pa;
    }
    __syncthreads();
    if (tid < 16) {   // publish self-tagged hh rows; land during attention
      float acc = 0.f;
      #pragma unroll
      for (int j = 0; j < 16; ++j) acc += s_scr[j * 16 + tid];
      cst64(hhrec + ((t + 1) & 1) * 4096 + b * 512 + blk * 16 + tid,
            ((unsigned long long)(unsigned)(t + 1) << 32) |
                __float_as_uint(acc));
    }
    // ---- stage 4: attention (bit-identical arithmetic) -------------------
    float a0 = 0.f, a1 = 0.f, a2 = 0.f, a3 = 0.f;
    #pragma unroll
    for (int h = 0; h < 128; h += 4) {
      float4 zq = *(const float4*)(s_qe + h);
      float z0 = zb[h+0] * zq.x, z1 = zb[h+1] * zq.y;
      float z2 = zb[h+2] * zq.z, z3 = zb[h+3] * zq.w;
      float r0 = __builtin_amdgcn_rcpf(z0 + 1.0f);
      float r1 = __builtin_amdgcn_rcpf(z1 + 1.0f);
      float r2 = __builtin_amdgcn_rcpf(z2 + 1.0f);
      float r3 = __builtin_amdgcn_rcpf(z3 + 1.0f);
      a0 = fmaf(watt[h+0], fmaf(-2.0f, r0, 1.0f), a0);
      a1 = fmaf(watt[h+1], fmaf(-2.0f, r1, 1.0f), a1);
      a2 = fmaf(watt[h+2], fmaf(-2.0f, r2, 1.0f), a2);
      a3 = fmaf(watt[h+3], fmaf(-2.0f, r3, 1.0f), a3);
    }
    float aq = ((a0 + a1) + (a2 + a3)) + 10000.0f;   // 2^-10-bucket quantized
    int kk = (int)((aq - 10000.0f) * 1024.0f);       // exact bucket index
    kk = kk < -8192 ? -8192 : (kk > 8191 ? 8191 : kk);
    unsigned key = ((unsigned)(kk + 8192) << 13) | (unsigned)(8191 - city);
    unsigned wmax = key;
    #pragma unroll
    for (int k = 1; k < 64; k <<= 1) {
      unsigned o = __shfl_xor(wmax, k);
      wmax = wmax > o ? wmax : o;
    }
    if (ln == 0) s_wk[wv] = wmax;
    __syncthreads();
    unsigned bkey = s_wk[0];
    bkey = bkey > s_wk[1] ? bkey : s_wk[1];
    bkey = bkey > s_wk[2] ? bkey : s_wk[2];
    bkey = bkey > s_wk[3] ? bkey : s_wk[3];
    if (tid == 0)   // EARLY publish to warm slot: consumers unblock on this
      cst64(krec + (t & 1) * 512 + b * 64 + blk,
            ((unsigned long long)(unsigned)(t + 1) << 32) | bkey);
    // ---- sumexp path (feeds frec only; off the group critical path) ------
    float m = fmaf((float)((int)((bkey >> 13) & 0x3FFFu) - 8192), kBucket,
                   10000.0f);
    float ee = __builtin_amdgcn_exp2f((aq - m) * kLog2e);   // exact diff
    #pragma unroll
    for (int k = 1; k < 64; k <<= 1) ee += __shfl_xor(ee, k);
    if (ln == 0) s_we[wv] = ee;
    __syncthreads();
    if (tid == 0) {
      float St = (s_we[0] + s_we[1]) + (s_we[2] + s_we[3]);
      unsigned pk = ((unsigned)(t + 1) << 27) | bkey;
      cst64(frec + (t & 1) * 512 + b * 64 + blk,
            ((unsigned long long)__float_as_uint(St) << 32) | pk);
    }
    // no end-of-step barrier: next iteration's spin is the barrier
  }
  // epilogue: outputs of the final step (group leader, wave 0)
  if (blk == 0 && tid < 64) {
    const unsigned long long* fp =
        frec + ((steps - 1) & 1) * 512 + b * 64 + (tid & 31);
    unsigned long long rv;
    const unsigned expect = (unsigned)steps;
    for (;;) {
      rv = cld64(fp);
      if (((unsigned)rv >> 27) == expect) break;
      __builtin_amdgcn_s_sleep(1);
    }
    unsigned wmax = (unsigned)rv & 0x07FFFFFFu;
    #pragma unroll
    for (int k = 1; k < 64; k <<= 1) {
      unsigned o = __shfl_xor(wmax, k);
      wmax = wmax > o ? wmax : o;
    }
    int   ix = 8191 - (int)(wmax & 0x1FFFu);
    int   kb = (int)(((unsigned)rv >> 13) & 0x3FFFu) - 8192;
    int   K  = (int)((wmax >> 13) & 0x3FFFu) - 8192;
    float Sb = __uint_as_float((unsigned)(rv >> 32));
    float term = Sb * __builtin_amdgcn_exp2f((float)(kb - K) * kBL2e);
    #pragma unroll
    for (int k = 1; k < 32; k <<= 1) term += __shfl_xor(term, k, 32);
    if (tid == 0) {
      out[b * steps + (steps - 1)] = (float)ix;
      out[NB * steps + b * steps + (steps - 1)] =
          -__builtin_amdgcn_logf(term) * kLn2;
    }
  }
}

extern "C" void kernel_launch(void* const* d_in, const int* in_sizes, int n_in,
                              void* d_out, int out_size, void* d_ws, size_t ws_size,
                              hipStream_t stream) {
  // ws layout (self-initializing; no memset — all records self-tagged):
  //   [0, 8K)    krec : u64[2][8*64]   (group stride 512 B, warm dbuf)
  //   [8K, 16K)  frec : u64[2][8*64]   (warm dbuf)
  //   [16K, 80K) hhrec: u64[2][8*512]  (group stride 4 KB, warm dbuf)
  unsigned long long* krec  = (unsigned long long*)d_ws;
  unsigned long long* frec  = (unsigned long long*)((char*)d_ws + 8192);
  unsigned long long* hhrec = (unsigned long long*)((char*)d_ws + 16384);
  drl4_kernel<<<dim3(256), dim3(256), 0, stream>>>(
      (const float*)d_in[0],  (const float*)d_in[1],
      (const float*)d_in[2],  (const float*)d_in[3],
      (const float*)d_in[4],  (const float*)d_in[5],
      (const float*)d_in[6],  (const float*)d_in[7],
      (const float*)d_in[8],  (const float*)d_in[9],
      (const float*)d_in[10], (const float*)d_in[11],
      (const float*)d_in[12], (const float*)d_in[13],
      (const float*)d_in[14], (const float*)d_in[15],
      (const float*)d_in[16], (const float*)d_in[17],
      (const float*)d_in[18], (const int*)d_in[19],
      (float*)d_out, krec, frec, hhrec);
}